// Round 1
// baseline (117523.853 us; speedup 1.0000x reference)
//
#include <hip/hip_runtime.h>
#include <hip/hip_bf16.h>

// LSTM: B=2048, T=512, I=5, H=128, then out[b] = h_n[b,:] @ W_lin + b_lin.
// Strategy: fp32, sequential over T, parallel over B.
//   - 512 threads/block, thread j owns gate row j (gate order i,f,g,o).
//   - W_hh row j (128 f32) resident in 32 float4 VGPRs per thread.
//   - BT=8 batch elems per block; h in LDS (broadcast reads), c in VGPRs.
//   - Input projection fused (I=5 -> 5 FMAs/gate), x double-buffered in LDS.

#define HH 128
#define II 5
#define TT 512
#define BT 8
#define NT 512

__device__ __forceinline__ float fast_exp2(float x) { return __builtin_amdgcn_exp2f(x); }
__device__ __forceinline__ float fast_rcp(float x)  { return __builtin_amdgcn_rcpf(x); }

// sigmoid(x) = 1/(1+e^-x); saturates correctly at +/-inf via exp2/rcp
__device__ __forceinline__ float sigmoid_f(float x) {
    float e = fast_exp2(x * -1.44269504f);
    return fast_rcp(1.0f + e);
}
// tanh(x) = 1 - 2/(1+e^{2x}); e overflow->inf->rcp 0->+1, underflow->0->rcp 1->-1
__device__ __forceinline__ float tanh_f(float x) {
    float e = fast_exp2(x * 2.88539008f);
    return 1.0f - 2.0f * fast_rcp(1.0f + e);
}

__global__ __launch_bounds__(NT, 2) void lstm_fused(
    const float* __restrict__ x,      // [B,T,I]
    const float* __restrict__ W_ih,   // [4H,I]
    const float* __restrict__ W_hh,   // [4H,H]
    const float* __restrict__ b_ih,   // [4H]
    const float* __restrict__ b_hh,   // [4H]
    const float* __restrict__ W_lin,  // [H]
    const float* __restrict__ b_lin,  // [1]
    float* __restrict__ out,          // [B]
    int B)
{
    __shared__ __align__(16) float h_s[BT][HH];     // 4 KB, broadcast-read in dot
    __shared__ float g_s[BT][4 * HH];               // 16 KB, activated gates
    __shared__ __align__(16) float x_s[2][BT][8];   // double-buffered x[b,t,:]

    const int tid = threadIdx.x;
    const int b0  = blockIdx.x * BT;
    const int j   = tid;                            // gate row 0..511

    // --- persistent per-thread state -------------------------------------
    float4 w[HH / 4];
    const float4* wrow = reinterpret_cast<const float4*>(W_hh + (size_t)j * HH);
    #pragma unroll
    for (int k = 0; k < HH / 4; ++k) w[k] = wrow[k];

    float wih[II];
    #pragma unroll
    for (int i = 0; i < II; ++i) wih[i] = W_ih[j * II + i];
    const float bias = b_ih[j] + b_hh[j];

    // h0 = 0
    for (int idx = tid; idx < BT * HH; idx += NT) (&h_s[0][0])[idx] = 0.0f;

    // x loader: 40 threads, one (bt,i) each
    const int  bt_x = tid / II, i_x = tid % II;
    const bool xloader = (tid < BT * II) && (b0 + bt_x < B);
    const float* xp = x + ((size_t)(b0 + bt_x) * TT) * II + i_x;
    if (xloader) x_s[0][bt_x][i_x] = xp[0];
    __syncthreads();

    float c_a = 0.0f, c_b = 0.0f;                   // cells (bt_u,hj) and (bt_u+4,hj)
    const int gt   = j >> 7;                        // wave-uniform gate type
    const int bt_u = tid >> 7;                      // 0..3
    const int hj_u = tid & (HH - 1);

    for (int t = 0; t < TT; ++t) {
        const int cur = t & 1;
        // prefetch next x (latency hidden behind the dot phase)
        float xnext = 0.0f;
        if (xloader && (t + 1) < TT) xnext = xp[(size_t)(t + 1) * II];

        // --- phase A: gate pre-activations -------------------------------
        float acc[BT];
        #pragma unroll
        for (int bt = 0; bt < BT; ++bt) {
            float a = bias;
            #pragma unroll
            for (int i = 0; i < II; ++i) a += wih[i] * x_s[cur][bt][i];
            const float4* hp = reinterpret_cast<const float4*>(&h_s[bt][0]);
            #pragma unroll
            for (int k = 0; k < HH / 4; ++k) {
                float4 hv = hp[k];                  // wave-uniform broadcast read
                a += w[k].x * hv.x;
                a += w[k].y * hv.y;
                a += w[k].z * hv.z;
                a += w[k].w * hv.w;
            }
            acc[bt] = a;
        }
        #pragma unroll
        for (int bt = 0; bt < BT; ++bt) {
            float v = (gt == 2) ? tanh_f(acc[bt]) : sigmoid_f(acc[bt]);
            g_s[bt][j] = v;                         // stride-1 store, no conflicts
        }
        __syncthreads();

        // --- phase B: cell update (2 cells per thread) -------------------
        {
            float i0  = g_s[bt_u][hj_u];
            float f0  = g_s[bt_u][HH + hj_u];
            float gg0 = g_s[bt_u][2 * HH + hj_u];
            float o0  = g_s[bt_u][3 * HH + hj_u];
            c_a = f0 * c_a + i0 * gg0;
            h_s[bt_u][hj_u] = o0 * tanh_f(c_a);

            const int btb = bt_u + 4;
            float i1  = g_s[btb][hj_u];
            float f1  = g_s[btb][HH + hj_u];
            float gg1 = g_s[btb][2 * HH + hj_u];
            float o1  = g_s[btb][3 * HH + hj_u];
            c_b = f1 * c_b + i1 * gg1;
            h_s[btb][hj_u] = o1 * tanh_f(c_b);
        }
        if (xloader && (t + 1) < TT) x_s[1 - cur][bt_x][i_x] = xnext;
        __syncthreads();
    }

    // --- epilogue: out[b] = h_n . W_lin + b_lin (wave w -> batch b0+w) ---
    const int wv = tid >> 6;
    const int lane = tid & 63;
    float p = W_lin[lane] * h_s[wv][lane] + W_lin[lane + 64] * h_s[wv][lane + 64];
    #pragma unroll
    for (int off = 32; off > 0; off >>= 1) p += __shfl_down(p, off, 64);
    if (lane == 0 && (b0 + wv) < B) out[b0 + wv] = p + b_lin[0];
}

extern "C" void kernel_launch(void* const* d_in, const int* in_sizes, int n_in,
                              void* d_out, int out_size, void* d_ws, size_t ws_size,
                              hipStream_t stream) {
    const float* x     = (const float*)d_in[0];
    const float* W_ih  = (const float*)d_in[1];
    const float* W_hh  = (const float*)d_in[2];
    const float* b_ih  = (const float*)d_in[3];
    const float* b_hh  = (const float*)d_in[4];
    const float* W_lin = (const float*)d_in[5];
    const float* b_lin = (const float*)d_in[6];
    float* out = (float*)d_out;

    const int B = in_sizes[0] / (TT * II);          // 2048
    const int grid = (B + BT - 1) / BT;             // 256 blocks
    lstm_fused<<<grid, NT, 0, stream>>>(x, W_ih, W_hh, b_ih, b_hh,
                                        W_lin, b_lin, out, B);
}

// Round 2
// 768.511 us; speedup vs baseline: 152.9241x; 152.9241x over previous
//
#include <hip/hip_runtime.h>
#include <hip/hip_bf16.h>

// LSTM B=2048,T=512,I=5,H=128 + linear -> [B,1], fp32 in/out.
// MFMA path: gates[16b x 512j] = Ahat[16 x 160] @ What^T per timestep, where
//   Ahat = [h (k=0..127) | x,5 (k=128..132) | zeros], What = [W_hh | W_ih | 0].
// mfma_f32_16x16x32_bf16, 5 k-chunks. Precision: h,x split hi+lo bf16 (exact),
// W single bf16 (static 2^-9 perturbation); fp32 bias added in cell phase.
// Gate-quad permutation: wave w owns cols {g*128 + w*16 + n, g=0..3}, so its 4
// acc tiles are i,f,g,o of its own (16 hj x 16 b) cells -> cell update fully
// in registers, c-state in 4 VGPRs/lane, no gate LDS.
// W frags 20x short8 = 80 VGPR; amdgpu_waves_per_eu(2,2) -> 256 VGPR budget
// (round-1 failure: compiler targeted 128 VGPRs and spilled 332 GB to scratch).

#define HH 128
#define II 5
#define TT 512
#define BT 16      // batch per block (MFMA M)
#define NT 512     // threads per block = 8 waves
#define KS 168     // padded A-row stride in bf16 elems (168*2B: +8 pad kills bank conflicts)

typedef __attribute__((ext_vector_type(8))) short bf16x8;
typedef __attribute__((ext_vector_type(4))) float f32x4;

__device__ __forceinline__ unsigned short f2bf(float f) {
    union { float f; unsigned u; } v; v.f = f;
    unsigned r = v.u + 0x7FFFu + ((v.u >> 16) & 1u);   // RNE
    return (unsigned short)(r >> 16);
}
__device__ __forceinline__ float bf2f(unsigned short h) {
    union { unsigned u; float f; } v; v.u = ((unsigned)h) << 16;
    return v.f;
}
__device__ __forceinline__ float sigmoid_f(float x) {
    float e = __builtin_amdgcn_exp2f(x * -1.44269504f);
    return __builtin_amdgcn_rcpf(1.0f + e);
}
__device__ __forceinline__ float tanh_f(float x) {
    float e = __builtin_amdgcn_exp2f(x * 2.88539008f);
    return 1.0f - 2.0f * __builtin_amdgcn_rcpf(1.0f + e);
}

__global__ __launch_bounds__(NT)
__attribute__((amdgpu_waves_per_eu(2, 2)))
void lstm_mfma(const float* __restrict__ x,      // [B,T,I]
               const float* __restrict__ W_ih,   // [4H,I]
               const float* __restrict__ W_hh,   // [4H,H]
               const float* __restrict__ b_ih,   // [4H]
               const float* __restrict__ b_hh,   // [4H]
               const float* __restrict__ W_lin,  // [H]
               const float* __restrict__ b_lin,  // [1]
               float* __restrict__ out,          // [B]
               int B)
{
    __shared__ short h_hi[BT][KS];   // bf16 bits, A-operand staging (hi part)
    __shared__ short h_lo[BT][KS];   // lo part
    __shared__ float hsc[BT][132];   // final-step exact h for the epilogue

    const int tid  = threadIdx.x;
    const int b0   = blockIdx.x * BT;
    const int lane = tid & 63;
    const int w    = tid >> 6;          // wave 0..7 -> owns hj in [16w,16w+16)
    const int n    = lane & 15;         // B-operand col / D col
    const int q    = lane >> 4;         // quad
    const int hcol = w * 16 + n;        // this lane's hj
    const int am   = n;                 // A-operand row (m) for frag loads
    const int q8   = q * 8;             // A/B k-offset within chunk

    // ---- W fragments: wf[gate][kc], B-layout: lane holds W^T[k=q8+e][n] -----
    // row j = gate*128 + hcol; k = kc*32 + q8 + e
    bf16x8 wf[4][5];
    #pragma unroll
    for (int g = 0; g < 4; ++g) {
        const int j = g * HH + hcol;
        #pragma unroll
        for (int kc = 0; kc < 4; ++kc) {
            const float4* p = reinterpret_cast<const float4*>(W_hh + (size_t)j * HH + kc * 32 + q8);
            float4 a = p[0], b2 = p[1];
            wf[g][kc][0] = (short)f2bf(a.x);  wf[g][kc][1] = (short)f2bf(a.y);
            wf[g][kc][2] = (short)f2bf(a.z);  wf[g][kc][3] = (short)f2bf(a.w);
            wf[g][kc][4] = (short)f2bf(b2.x); wf[g][kc][5] = (short)f2bf(b2.y);
            wf[g][kc][6] = (short)f2bf(b2.z); wf[g][kc][7] = (short)f2bf(b2.w);
        }
        #pragma unroll
        for (int e = 0; e < 8; ++e) {
            int kl = q8 + e;                       // 0..31 within chunk 4
            float v = (kl < II) ? W_ih[j * II + kl] : 0.0f;
            wf[g][4][e] = (short)f2bf(v);
        }
    }
    float bg[4];
    #pragma unroll
    for (int g = 0; g < 4; ++g) bg[g] = b_ih[g * HH + hcol] + b_hh[g * HH + hcol];

    // ---- zero A staging (h0 = 0, tail of chunk 4 = 0) -----------------------
    for (int idx = tid; idx < BT * KS; idx += NT) {
        (&h_hi[0][0])[idx] = 0; (&h_lo[0][0])[idx] = 0;
    }
    // ---- x loader: 80 threads, one (bt,i) each ------------------------------
    const int  btx = tid / II, ix = tid % II;
    const bool xload = (tid < BT * II) && (b0 + btx < B);
    const float* xg = x + ((size_t)(b0 + btx) * TT) * II + ix;
    if (xload) {
        float x0 = xg[0];
        unsigned short hb = f2bf(x0);
        h_hi[btx][HH + ix] = (short)hb;
        h_lo[btx][HH + ix] = (short)f2bf(x0 - bf2f(hb));
    }
    __syncthreads();

    float cc[4] = {0.f, 0.f, 0.f, 0.f};   // cell state, C-layout (m = q*4+r, hj = hcol)

    #pragma unroll 1
    for (int t = 0; t < TT; ++t) {
        // prefetch next x (consumed after the barrier)
        float xv = 0.0f;
        const bool pf = xload && (t + 1 < TT);
        if (pf) xv = xg[(size_t)(t + 1) * II];

        // ---- MFMA phase: acc[g] += (A_hi + A_lo) . wf[g] --------------------
        f32x4 acc[4];
        #pragma unroll
        for (int g = 0; g < 4; ++g) {
            #pragma unroll
            for (int e = 0; e < 4; ++e) acc[g][e] = 0.0f;
        }
        #pragma unroll
        for (int kc = 0; kc < 5; ++kc) {
            bf16x8 ah = *reinterpret_cast<const bf16x8*>(&h_hi[am][kc * 32 + q8]);
            bf16x8 al = *reinterpret_cast<const bf16x8*>(&h_lo[am][kc * 32 + q8]);
            #pragma unroll
            for (int g = 0; g < 4; ++g) {
                acc[g] = __builtin_amdgcn_mfma_f32_16x16x32_bf16(ah, wf[g][kc], acc[g], 0, 0, 0);
                acc[g] = __builtin_amdgcn_mfma_f32_16x16x32_bf16(al, wf[g][kc], acc[g], 0, 0, 0);
            }
        }
        __syncthreads();   // all A-reads done; h buffers now writable

        // ---- cell phase: 4 cells/lane, fully in registers -------------------
        #pragma unroll
        for (int r = 0; r < 4; ++r) {
            const int m = q * 4 + r;
            float ig = acc[0][r] + bg[0];
            float fg = acc[1][r] + bg[1];
            float gg = acc[2][r] + bg[2];
            float og = acc[3][r] + bg[3];
            float iv = sigmoid_f(ig);
            float fv = sigmoid_f(fg);
            float gv = tanh_f(gg);
            float ov = sigmoid_f(og);
            cc[r] = fv * cc[r] + iv * gv;
            float hv = ov * tanh_f(cc[r]);
            unsigned short hb = f2bf(hv);
            h_hi[m][hcol] = (short)hb;
            h_lo[m][hcol] = (short)f2bf(hv - bf2f(hb));
            if (t == TT - 1) hsc[m][hcol] = hv;
        }
        if (pf) {
            unsigned short xb = f2bf(xv);
            h_hi[btx][HH + ix] = (short)xb;
            h_lo[btx][HH + ix] = (short)f2bf(xv - bf2f(xb));
        }
        __syncthreads();   // h_t ready for next step
    }

    // ---- epilogue: out[b] = hsc[b,:] . W_lin + b_lin ------------------------
    const int eb = tid >> 5;      // 0..15
    const int es = tid & 31;      // 0..31, half-wave group
    float4 hv4 = *reinterpret_cast<const float4*>(&hsc[eb][es * 4]);
    float4 wv4 = reinterpret_cast<const float4*>(W_lin)[es];
    float p = hv4.x * wv4.x + hv4.y * wv4.y + hv4.z * wv4.z + hv4.w * wv4.w;
    #pragma unroll
    for (int off = 16; off > 0; off >>= 1) p += __shfl_down(p, off, 32);
    if (es == 0 && (b0 + eb) < B) out[b0 + eb] = p + b_lin[0];
}

extern "C" void kernel_launch(void* const* d_in, const int* in_sizes, int n_in,
                              void* d_out, int out_size, void* d_ws, size_t ws_size,
                              hipStream_t stream) {
    const float* x     = (const float*)d_in[0];
    const float* W_ih  = (const float*)d_in[1];
    const float* W_hh  = (const float*)d_in[2];
    const float* b_ih  = (const float*)d_in[3];
    const float* b_hh  = (const float*)d_in[4];
    const float* W_lin = (const float*)d_in[5];
    const float* b_lin = (const float*)d_in[6];
    float* out = (float*)d_out;

    const int B = in_sizes[0] / (TT * II);          // 2048
    const int grid = (B + BT - 1) / BT;             // 128 blocks
    lstm_mfma<<<grid, NT, 0, stream>>>(x, W_ih, W_hh, b_ih, b_hh,
                                       W_lin, b_lin, out, B);
}